// Round 10
// baseline (261.820 us; speedup 1.0000x reference)
//
#include <hip/hip_runtime.h>

constexpr int NS = 131072;
constexpr int D  = 128;
constexpr int K  = 512;
constexpr int FLAG_CAP  = 65536;
constexpr int FLAG2_CAP = 32768;
constexpr float TAU1 = 0.05f;     // f16 single-pass: sigma_diff ~ 0.0065 -> ~8 sigma
constexpr float TAU2 = 2e-3f;     // f16 3-term: sigma ~ 2e-5 -> 100 sigma
constexpr int SEG = 32;
constexpr int NB = 64;            // scatter blocks
constexpr int ITEMS = NS / NB;    // 2048 items per scatter block
constexpr float FIXSCALE = 1048576.0f;       // 2^20
constexpr double INVFIX  = 1.0 / 1048576.0;

using half8 = __attribute__((ext_vector_type(8))) _Float16;
using f32x4 = __attribute__((ext_vector_type(4))) float;

// ws layout (bytes):
// 0:       double lossSum
// 8:       double x2Sum[8]    -> 72
// 72:      int flagCount; 76: int flagCount2 -> 80
// 80:      float c2[K]        -> 2128
// 2128:    int counts[K]      -> 4176
// 4176:    float mindist[NS]  -> 528464   (min1 WITHOUT ||x||^2)
// 528464:  int labI[NS]       -> 1052752
// 1052752: int flags[65536]   -> 1314896
// 1314896: int flags2[32768]  -> 1445968
// 1445968: int H[NB*K]        -> 1577040
// 1577040: int bucket[NS]     -> 2101328
// 2101328: u64 acc[K*D]       -> 2625616
// 2625616: f16 Ch[K*D]        -> 2756688
// 2756688: f16 Cl[K*D]        -> 2887760

union H4 { short4 s4; _Float16 h[4]; };
union H8 { half8 v; _Float16 h[8]; };

// Fused: c2 = ||c||^2 (f32) and C -> f16 (hi, lo) limbs. One wave per center.
__global__ void k_prep(const float* __restrict__ C, float* __restrict__ c2,
                       _Float16* __restrict__ Ch, _Float16* __restrict__ Cl) {
    int wave = (blockIdx.x * blockDim.x + threadIdx.x) >> 6;
    int lane = threadIdx.x & 63;
    const float* ck = C + (size_t)wave * D;
    float a = ck[lane], b = ck[lane + 64];
    _Float16 ha = (_Float16)a, hb = (_Float16)b;
    size_t o = (size_t)wave * D + lane;
    Ch[o] = ha;        Cl[o] = (_Float16)(a - (float)ha);
    Ch[o + 64] = hb;   Cl[o + 64] = (_Float16)(b - (float)hb);
    float s = fmaf(a, a, b * b);
    #pragma unroll
    for (int off = 32; off > 0; off >>= 1) s += __shfl_xor(s, off, 64);
    if (lane == 0) c2[wave] = s;
}

// f16 single-pass MFMA distance + per-sample argmin. SAMPLE-STATIONARY:
// A = this wave's 16 samples (16 VGPR, loaded once from global), B = centers
// streamed from L2. Live set ~60 VGPR -> nothing for the allocator to spill
// (R7-R9 lesson: any ~64-VGPR held fragment array gets spilled to scratch).
// D layout: row = sample = (lane>>4)*4+reg, col = center = lane&15.
__global__ __launch_bounds__(256) void k_dist(
    const float* __restrict__ X, const _Float16* __restrict__ Ch,
    const float* __restrict__ c2,
    float* __restrict__ labF, float* __restrict__ mindist, int* __restrict__ labI,
    int* __restrict__ flags, int* __restrict__ flagCount)
{
    int tid = threadIdx.x;
    int wave = tid >> 6, lane = tid & 63;
    int l15 = lane & 15, lk = lane >> 4;
    int sbase = blockIdx.x * 64 + wave * 16;
    int srow = sbase + l15;                 // this lane's A-row (sample)

    // ---- A fragments: 16 samples, f32 -> f16, once (16 VGPR) ----
    half8 xa[4];
    const float* xp = X + (size_t)srow * D + lk * 8;
    #pragma unroll
    for (int kk = 0; kk < 4; ++kk) {
        float4 a = *(const float4*)(xp + kk * 32);
        float4 b = *(const float4*)(xp + kk * 32 + 4);
        H8 u;
        u.h[0] = (_Float16)a.x; u.h[1] = (_Float16)a.y;
        u.h[2] = (_Float16)a.z; u.h[3] = (_Float16)a.w;
        u.h[4] = (_Float16)b.x; u.h[5] = (_Float16)b.y;
        u.h[6] = (_Float16)b.z; u.h[7] = (_Float16)b.w;
        xa[kk] = u.v;
    }

    float m1[4], m2[4]; int ag[4];
    #pragma unroll
    for (int r = 0; r < 4; ++r) { m1[r] = 3.4e38f; m2[r] = 3.4e38f; ag[r] = 0; }

    #pragma unroll 2
    for (int ct = 0; ct < 32; ++ct) {       // 32 center-tiles of 16
        int ci = ct * 16 + l15;             // this lane's center (D col)
        const half8* pcb = (const half8*)(Ch + (size_t)ci * D + lk * 8);
        half8 b0 = pcb[0], b1 = pcb[4], b2 = pcb[8], b3 = pcb[12];
        float cc = c2[ci];
        f32x4 acc = (f32x4){0.f, 0.f, 0.f, 0.f};
        acc = __builtin_amdgcn_mfma_f32_16x16x32_f16(xa[0], b0, acc, 0, 0, 0);
        acc = __builtin_amdgcn_mfma_f32_16x16x32_f16(xa[1], b1, acc, 0, 0, 0);
        acc = __builtin_amdgcn_mfma_f32_16x16x32_f16(xa[2], b2, acc, 0, 0, 0);
        acc = __builtin_amdgcn_mfma_f32_16x16x32_f16(xa[3], b3, acc, 0, 0, 0);
        #pragma unroll
        for (int r = 0; r < 4; ++r) {
            float s = fmaf(-2.f, acc[r], cc);
            bool b = s < m1[r];             // strict: earliest center wins ties
            m2[r] = b ? m1[r] : fminf(m2[r], s);
            m1[r] = b ? s : m1[r];
            ag[r] = b ? ci : ag[r];
        }
    }

    // ---- per-sample reduce over the 16 center-columns (lanes l15=0..15) ----
    #pragma unroll
    for (int off = 1; off <= 8; off <<= 1)
        #pragma unroll
        for (int r = 0; r < 4; ++r) {
            float o1 = __shfl_xor(m1[r], off, 64);
            float o2 = __shfl_xor(m2[r], off, 64);
            int   oa = __shfl_xor(ag[r], off, 64);
            bool b = (o1 < m1[r]) || (o1 == m1[r] && oa < ag[r]);
            float lo1 = b ? o1 : m1[r];
            float hi1 = b ? m1[r] : o1;
            m2[r] = fminf(fminf(m2[r], o2), hi1);
            m1[r] = lo1;
            ag[r] = b ? oa : ag[r];
        }

    // ---- output: lane l15==0 of each row-group writes its 4 samples ----
    if (l15 == 0) {
        #pragma unroll
        for (int r = 0; r < 4; ++r) {
            int i = sbase + lk * 4 + r;
            labF[i] = (float)ag[r];
            labI[i] = ag[r];
            mindist[i] = m1[r];             // without ||x||^2 (added at loss)
            if (m2[r] - m1[r] < TAU1) {
                int p = atomicAdd(flagCount, 1);
                if (p < FLAG_CAP) flags[p] = i;
            }
        }
    }
}

// Middle stage: gather flagged samples 64/tile, re-resolve with 3-term f16
// Markidis MFMA (xh*ch + xh*cl + xl*ch). Grid-stride; nf read on device.
__global__ __launch_bounds__(256, 2) void k_mid(
    const float* __restrict__ X, const _Float16* __restrict__ Ch,
    const _Float16* __restrict__ Cl, const float* __restrict__ c2,
    const int* __restrict__ flagCount, const int* __restrict__ flags,
    float* __restrict__ labF, float* __restrict__ mindist, int* __restrict__ labI,
    int* __restrict__ flags2, int* __restrict__ flagCount2)
{
    __shared__ _Float16 Ah[64][136];
    __shared__ _Float16 Al[64][136];
    __shared__ float red1[4][64];
    __shared__ float red2[4][64];
    __shared__ int   reda[4][64];
    __shared__ int   sidx[64];

    int nf = *flagCount;
    if (nf > FLAG_CAP) nf = FLAG_CAP;
    int ntile = (nf + 63) >> 6;
    int tid = threadIdx.x;
    int wave = tid >> 6, lane = tid & 63;
    int l15 = lane & 15, lk = lane >> 4;

    for (int t = blockIdx.x; t < ntile; t += gridDim.x) {
        if (tid < 64) {
            int p = t * 64 + tid;
            sidx[tid] = flags[p < nf ? p : nf - 1];   // tail: duplicate last (idempotent)
        }
        __syncthreads();
        {
            int row = tid >> 2, part = tid & 3;
            const float4* src = (const float4*)(X + (size_t)sidx[row] * D + part * 32);
            #pragma unroll
            for (int j = 0; j < 8; ++j) {
                float4 v = src[j];
                H4 uh, ul;
                uh.h[0] = (_Float16)v.x; ul.h[0] = (_Float16)(v.x - (float)uh.h[0]);
                uh.h[1] = (_Float16)v.y; ul.h[1] = (_Float16)(v.y - (float)uh.h[1]);
                uh.h[2] = (_Float16)v.z; ul.h[2] = (_Float16)(v.z - (float)uh.h[2]);
                uh.h[3] = (_Float16)v.w; ul.h[3] = (_Float16)(v.w - (float)uh.h[3]);
                *(short4*)&Ah[row][part * 32 + j * 4] = uh.s4;
                *(short4*)&Al[row][part * 32 + j * 4] = ul.s4;
            }
        }
        __syncthreads();

        float m1[4], m2[4]; int ag[4];
        #pragma unroll
        for (int n = 0; n < 4; ++n) { m1[n] = 3.4e38f; m2[n] = 3.4e38f; ag[n] = 0; }

        for (int chunk = 0; chunk < 8; ++chunk) {
            int cb = chunk * 64 + wave * 16;
            const half8* pch = (const half8*)(Ch + (size_t)(cb + l15) * D + lk * 8);
            const half8* pcl = (const half8*)(Cl + (size_t)(cb + l15) * D + lk * 8);
            half8 ah[4], al[4];
            #pragma unroll
            for (int kk = 0; kk < 4; ++kk) { ah[kk] = pch[kk * 4]; al[kk] = pcl[kk * 4]; }
            f32x4 acc[4];
            #pragma unroll
            for (int n = 0; n < 4; ++n) acc[n] = (f32x4){0.f, 0.f, 0.f, 0.f};
            #pragma unroll
            for (int kk = 0; kk < 4; ++kk) {
                half8 xh[4], xl[4];
                #pragma unroll
                for (int n = 0; n < 4; ++n) {
                    xh[n] = *(const half8*)&Ah[n * 16 + l15][kk * 32 + lk * 8];
                    xl[n] = *(const half8*)&Al[n * 16 + l15][kk * 32 + lk * 8];
                }
                #pragma unroll
                for (int n = 0; n < 4; ++n)
                    acc[n] = __builtin_amdgcn_mfma_f32_16x16x32_f16(ah[kk], xh[n], acc[n], 0, 0, 0);
                #pragma unroll
                for (int n = 0; n < 4; ++n)
                    acc[n] = __builtin_amdgcn_mfma_f32_16x16x32_f16(al[kk], xh[n], acc[n], 0, 0, 0);
                #pragma unroll
                for (int n = 0; n < 4; ++n)
                    acc[n] = __builtin_amdgcn_mfma_f32_16x16x32_f16(ah[kk], xl[n], acc[n], 0, 0, 0);
            }
            float cc[4];
            #pragma unroll
            for (int r = 0; r < 4; ++r) cc[r] = c2[cb + lk * 4 + r];
            #pragma unroll
            for (int n = 0; n < 4; ++n)
                #pragma unroll
                for (int r = 0; r < 4; ++r) {
                    float s = fmaf(-2.f, acc[n][r], cc[r]);
                    int ci = cb + lk * 4 + r;
                    bool b = s < m1[n];
                    m2[n] = b ? m1[n] : fminf(m2[n], s);
                    m1[n] = b ? s : m1[n];
                    ag[n] = b ? ci : ag[n];
                }
        }

        #pragma unroll
        for (int off = 16; off <= 32; off <<= 1)
            #pragma unroll
            for (int n = 0; n < 4; ++n) {
                float o1 = __shfl_xor(m1[n], off, 64);
                float o2 = __shfl_xor(m2[n], off, 64);
                int   oa = __shfl_xor(ag[n], off, 64);
                bool b = (o1 < m1[n]) || (o1 == m1[n] && oa < ag[n]);
                float lo1 = b ? o1 : m1[n];
                float hi1 = b ? m1[n] : o1;
                m2[n] = fminf(fminf(m2[n], o2), hi1);
                m1[n] = lo1;
                ag[n] = b ? oa : ag[n];
            }
        if (lane < 16) {
            #pragma unroll
            for (int n = 0; n < 4; ++n) {
                red1[wave][n * 16 + l15] = m1[n];
                red2[wave][n * 16 + l15] = m2[n];
                reda[wave][n * 16 + l15] = ag[n];
            }
        }
        __syncthreads();

        if (tid < 64) {
            float M1 = red1[0][tid], M2 = red2[0][tid]; int A = reda[0][tid];
            #pragma unroll
            for (int w = 1; w < 4; ++w) {
                float o1 = red1[w][tid], o2 = red2[w][tid]; int oa = reda[w][tid];
                bool b = (o1 < M1) || (o1 == M1 && oa < A);
                float lo1 = b ? o1 : M1;
                float hi1 = b ? M1 : o1;
                M2 = fminf(fminf(M2, o2), hi1);
                M1 = lo1;
                A = b ? oa : A;
            }
            int i = sidx[tid];
            labF[i] = (float)A;
            labI[i] = A;
            mindist[i] = M1;
            bool fl = (M2 - M1 < TAU2);
            unsigned long long mask = __ballot(fl);
            int nfl = (int)__popcll(mask);
            int base = 0;
            if (tid == 0 && nfl) base = atomicAdd(flagCount2, nfl);
            base = __shfl(base, 0, 64);
            if (fl) {
                int pos = base + (int)__popcll(mask & ((1ull << tid) - 1ull));
                if (pos < FLAG2_CAP) flags2[pos] = i;
            }
        }
        __syncthreads();   // protect sidx/Ah/Al before next tile
    }
}

__global__ void k_refine(const float* __restrict__ X, const float* __restrict__ C,
                         const int* __restrict__ flagCount2, const int* __restrict__ flags2,
                         float* __restrict__ labF, float* __restrict__ mindist,
                         int* __restrict__ labI)
{
    int nf = *flagCount2;
    if (nf > FLAG2_CAP) nf = FLAG2_CAP;
    int lane = threadIdx.x;  // block of 64 = 1 wave
    for (int f = blockIdx.x; f < nf; f += gridDim.x) {
        int i = flags2[f];
        const float* xr = X + (size_t)i * D;
        double best = 1e300;
        int bestk = K;
        for (int k = lane; k < K; k += 64) {
            const float* ck = C + (size_t)k * D;
            double dot = 0.0, cc = 0.0;
            for (int d = 0; d < D; ++d) {
                double cd = (double)ck[d];
                dot = fma((double)xr[d], cd, dot);
                cc  = fma(cd, cd, cc);
            }
            double s = cc - 2.0 * dot;
            if (s < best) { best = s; bestk = k; }
        }
        #pragma unroll
        for (int off = 32; off > 0; off >>= 1) {
            double ob = __shfl_xor(best, off, 64);
            int okk   = __shfl_xor(bestk, off, 64);
            if (ob < best || (ob == best && okk < bestk)) { best = ob; bestk = okk; }
        }
        if (lane == 0) {
            labF[i] = (float)bestk;
            labI[i] = bestk;
            mindist[i] = (float)best;
        }
    }
}

// Per-block histogram via LDS atomics + fused loss partial sum.
__global__ __launch_bounds__(256) void k_bhl(const int* __restrict__ labI,
                                             const float* __restrict__ mindist,
                                             int* __restrict__ H,
                                             double* __restrict__ lossSum) {
    __shared__ int h[K];
    __shared__ double shd[4];
    for (int c = threadIdx.x; c < K; c += 256) h[c] = 0;
    __syncthreads();
    int base = blockIdx.x * ITEMS;
    double s = 0.0;
    #pragma unroll
    for (int it = 0; it < ITEMS / 256; ++it) {
        int i = base + it * 256 + threadIdx.x;
        atomicAdd(&h[labI[i]], 1);
        s += (double)mindist[i];
    }
    __syncthreads();
    for (int c = threadIdx.x; c < K; c += 256) H[blockIdx.x * K + c] = h[c];
    #pragma unroll
    for (int off = 32; off > 0; off >>= 1) s += __shfl_xor(s, off, 64);
    int wid = threadIdx.x >> 6, lane = threadIdx.x & 63;
    if (lane == 0) shd[wid] = s;
    __syncthreads();
    if (threadIdx.x == 0)
        atomicAdd(lossSum, (shd[0] + shd[1]) + (shd[2] + shd[3]));
}

// Column-scan H (per center over blocks) + block-wide prefix scan of totals.
__global__ void k_sc(int* __restrict__ H, int* __restrict__ counts) {
    __shared__ int sh[K];
    int c = threadIdx.x;
    int run = 0;
    for (int b = 0; b < NB; ++b) { int t = H[b * K + c]; H[b * K + c] = run; run += t; }
    counts[c] = run;
    sh[c] = run;
    __syncthreads();
    int my = run;
    for (int off = 1; off < K; off <<= 1) {
        int v = (c >= off) ? sh[c - off] : 0;
        __syncthreads();
        sh[c] += v;
        __syncthreads();
    }
    int excl = sh[c] - my;
    for (int b = 0; b < NB; ++b) H[b * K + c] += excl;
}

// Scatter with per-block LDS cursors — zero global atomics.
__global__ __launch_bounds__(256) void k_scatter2(const int* __restrict__ labI,
                                                  const int* __restrict__ H,
                                                  int* __restrict__ bucket) {
    __shared__ int cur[K];
    for (int c = threadIdx.x; c < K; c += 256) cur[c] = H[blockIdx.x * K + c];
    __syncthreads();
    int base = blockIdx.x * ITEMS;
    #pragma unroll
    for (int it = 0; it < ITEMS / 256; ++it) {
        int i = base + it * 256 + threadIdx.x;
        int pos = atomicAdd(&cur[labI[i]], 1);
        bucket[pos] = i;
    }
}

// Fixed segments of sorted bucket; int64 fixed-point accumulation is
// order-independent -> deterministic despite nondeterministic scatter order.
// Also accumulates sum ||x||^2 (every X row visited exactly once here).
__global__ __launch_bounds__(128) void k_sumseg(
    const float* __restrict__ X, const int* __restrict__ labI,
    const int* __restrict__ bucket, unsigned long long* __restrict__ acc,
    double* __restrict__ x2Sum)
{
    int d = threadIdx.x;
    int beg = blockIdx.x * SEG;
    long long s = 0;
    double s2 = 0.0;
    int prev = -1;
    for (int j = beg; j < beg + SEG; ++j) {
        int idx = bucket[j];
        int lab = labI[idx];                 // uniform across the block
        if (lab != prev) {
            if (prev >= 0) atomicAdd(&acc[(size_t)prev * D + d], (unsigned long long)s);
            s = 0; prev = lab;
        }
        float v = X[(size_t)idx * D + d];
        s += (long long)__float2int_rn(v * FIXSCALE);
        s2 = fma((double)v, (double)v, s2);
    }
    if (prev >= 0) atomicAdd(&acc[(size_t)prev * D + d], (unsigned long long)s);
    #pragma unroll
    for (int off = 32; off > 0; off >>= 1) s2 += __shfl_xor(s2, off, 64);
    __shared__ double shx[2];
    int wid = d >> 6;
    if ((d & 63) == 0) shx[wid] = s2;
    __syncthreads();
    if (d == 0) atomicAdd(&x2Sum[blockIdx.x & 7], shx[0] + shx[1]);
}

__global__ void k_avg(const float* __restrict__ C, const int* __restrict__ cnt,
                      const int* __restrict__ counts,
                      const unsigned long long* __restrict__ acc,
                      float* __restrict__ outC, float* __restrict__ outCnt,
                      const double* __restrict__ lossSum,
                      const double* __restrict__ x2Sum, float* __restrict__ outLoss)
{
    int t = blockIdx.x * blockDim.x + threadIdx.x;   // over K*D
    int c = t >> 7, d = t & 127;
    double s = (double)(long long)acc[t] * INVFIX;
    int m = counts[c], n0 = cnt[c];
    double nm = (double)(n0 + m);
    outC[t] = (float)(((double)n0 * (double)C[t] + s) / nm);
    if (d == 0) outCnt[c] = (float)(n0 + m);
    if (t == 0) {
        double x2 = 0.0;
        #pragma unroll
        for (int j = 0; j < 8; ++j) x2 += x2Sum[j];
        outLoss[0] = (float)((*lossSum + x2) / (double)NS);
    }
}

extern "C" void kernel_launch(void* const* d_in, const int* in_sizes, int n_in,
                              void* d_out, int out_size, void* d_ws, size_t ws_size,
                              hipStream_t stream)
{
    const float* X  = (const float*)d_in[0];
    const float* C  = (const float*)d_in[1];
    const int* cnt  = (const int*)d_in[2];

    float* out     = (float*)d_out;
    float* outLoss = out;
    float* outLab  = out + 1;
    float* outCen  = out + 1 + NS;
    float* outCnt  = out + 1 + NS + (size_t)K * D;

    char* ws = (char*)d_ws;
    double* lossSum = (double*)(ws + 0);
    double* x2Sum   = (double*)(ws + 8);
    int* flagCount  = (int*)(ws + 72);
    int* flagCount2 = (int*)(ws + 76);
    float* c2       = (float*)(ws + 80);
    int* counts     = (int*)(ws + 2128);
    float* mindist  = (float*)(ws + 4176);
    int* labI       = (int*)(ws + 528464);
    int* flags      = (int*)(ws + 1052752);
    int* flags2     = (int*)(ws + 1314896);
    int* H          = (int*)(ws + 1445968);
    int* bucket     = (int*)(ws + 1577040);
    unsigned long long* acc = (unsigned long long*)(ws + 2101328);
    _Float16* Ch    = (_Float16*)(ws + 2625616);
    _Float16* Cl    = (_Float16*)(ws + 2756688);

    hipMemsetAsync(d_ws, 0, 80, stream);                        // lossSum, x2Sum, flagCounts
    hipMemsetAsync(ws + 2101328, 0, (size_t)K * D * 8, stream); // acc
    k_prep<<<K / 4, 256, 0, stream>>>(C, c2, Ch, Cl);
    k_dist<<<NS / 64, 256, 0, stream>>>(X, Ch, c2, outLab, mindist, labI, flags, flagCount);
    k_mid<<<512, 256, 0, stream>>>(X, Ch, Cl, c2, flagCount, flags,
                                   outLab, mindist, labI, flags2, flagCount2);
    k_refine<<<2048, 64, 0, stream>>>(X, C, flagCount2, flags2, outLab, mindist, labI);
    k_bhl<<<NB, 256, 0, stream>>>(labI, mindist, H, lossSum);
    k_sc<<<1, K, 0, stream>>>(H, counts);
    k_scatter2<<<NB, 256, 0, stream>>>(labI, H, bucket);
    k_sumseg<<<NS / SEG, 128, 0, stream>>>(X, labI, bucket, acc, x2Sum);
    k_avg<<<K * D / 256, 256, 0, stream>>>(C, cnt, counts, acc, outCen, outCnt,
                                           lossSum, x2Sum, outLoss);
}

// Round 11
// 200.716 us; speedup vs baseline: 1.3044x; 1.3044x over previous
//
#include <hip/hip_runtime.h>

constexpr int NS = 131072;
constexpr int D  = 128;
constexpr int K  = 512;
constexpr int FLAG_CAP  = 65536;
constexpr int FLAG2_CAP = 32768;
constexpr float TAU1 = 0.05f;     // f16 single-pass: sigma_diff ~ 0.0065 -> ~8 sigma
constexpr float TAU2 = 2e-3f;     // f16 3-term: sigma ~ 2e-5 -> 100 sigma
constexpr int SEG = 32;
constexpr int NB = 64;            // scatter blocks
constexpr int ITEMS = NS / NB;    // 2048 items per scatter block
constexpr float FIXSCALE = 1048576.0f;       // 2^20
constexpr double INVFIX  = 1.0 / 1048576.0;

using half8 = __attribute__((ext_vector_type(8))) _Float16;
using f32x4 = __attribute__((ext_vector_type(4))) float;

// ws layout (bytes):
// 0:       double lossSum
// 8:       double x2Sum[8]    -> 72
// 72:      int flagCount; 76: int flagCount2 -> 80
// 80:      float c2[K]        -> 2128
// 2128:    int counts[K]      -> 4176
// 4176:    float mindist[NS]  -> 528464   (min1 WITHOUT ||x||^2)
// 528464:  int labI[NS]       -> 1052752
// 1052752: int flags[65536]   -> 1314896
// 1314896: int flags2[32768]  -> 1445968
// 1445968: int H[NB*K]        -> 1577040
// 1577040: int bucket[NS]     -> 2101328
// 2101328: u64 acc[K*D]       -> 2625616
// 2625616: f16 Ch[K*D]        -> 2756688
// 2756688: f16 Cl[K*D]        -> 2887760

union H4 { short4 s4; _Float16 h[4]; };
union H8 { half8 v; _Float16 h[8]; };

// Fused: c2 = ||c||^2 (f32) and C -> f16 (hi, lo) limbs. One wave per center.
__global__ void k_prep(const float* __restrict__ C, float* __restrict__ c2,
                       _Float16* __restrict__ Ch, _Float16* __restrict__ Cl) {
    int wave = (blockIdx.x * blockDim.x + threadIdx.x) >> 6;
    int lane = threadIdx.x & 63;
    const float* ck = C + (size_t)wave * D;
    float a = ck[lane], b = ck[lane + 64];
    _Float16 ha = (_Float16)a, hb = (_Float16)b;
    size_t o = (size_t)wave * D + lane;
    Ch[o] = ha;        Cl[o] = (_Float16)(a - (float)ha);
    Ch[o + 64] = hb;   Cl[o + 64] = (_Float16)(b - (float)hb);
    float s = fmaf(a, a, b * b);
    #pragma unroll
    for (int off = 32; off > 0; off >>= 1) s += __shfl_xor(s, off, 64);
    if (lane == 0) c2[wave] = s;
}

// f16 single-pass MFMA distance + per-sample argmin. Sample-stationary
// (R10, spill-free: live ~58 VGPR) + LDS-staged center chunks shared by the
// block's 4 waves (cuts the 1 GB per-wave L2 center stream to 256 MB).
// D layout: row = sample = (lane>>4)*4+reg, col = center = lane&15.
__global__ __launch_bounds__(256) void k_dist(
    const float* __restrict__ X, const _Float16* __restrict__ Ch,
    const float* __restrict__ c2,
    float* __restrict__ labF, float* __restrict__ mindist, int* __restrict__ labI,
    int* __restrict__ flags, int* __restrict__ flagCount)
{
    __shared__ _Float16 Cs[64][136];        // 272 B rows: 16B-aligned, even banks

    int tid = threadIdx.x;
    int wave = tid >> 6, lane = tid & 63;
    int l15 = lane & 15, lk = lane >> 4;
    int sbase = blockIdx.x * 64 + wave * 16;
    int srow = sbase + l15;                 // this lane's A-row (sample)

    // ---- A fragments: 16 samples, f32 -> f16, once (16 VGPR) ----
    half8 xa[4];
    const float* xp = X + (size_t)srow * D + lk * 8;
    #pragma unroll
    for (int kk = 0; kk < 4; ++kk) {
        float4 a = *(const float4*)(xp + kk * 32);
        float4 b = *(const float4*)(xp + kk * 32 + 4);
        H8 u;
        u.h[0] = (_Float16)a.x; u.h[1] = (_Float16)a.y;
        u.h[2] = (_Float16)a.z; u.h[3] = (_Float16)a.w;
        u.h[4] = (_Float16)b.x; u.h[5] = (_Float16)b.y;
        u.h[6] = (_Float16)b.z; u.h[7] = (_Float16)b.w;
        xa[kk] = u.v;
    }

    float m1[4], m2[4]; int ag[4];
    #pragma unroll
    for (int r = 0; r < 4; ++r) { m1[r] = 3.4e38f; m2[r] = 3.4e38f; ag[r] = 0; }

    int crow = tid >> 2, cpart = tid & 3;   // staging role: 4 threads per center row
    for (int chunk = 0; chunk < 8; ++chunk) {
        // ---- stage 64 centers (16 KB) into LDS, cooperatively ----
        const int4* src = (const int4*)(Ch + (size_t)(chunk * 64 + crow) * D + cpart * 32);
        int4 v0 = src[0], v1 = src[1], v2 = src[2], v3 = src[3];
        *(int4*)&Cs[crow][cpart * 32]      = v0;
        *(int4*)&Cs[crow][cpart * 32 + 8]  = v1;
        *(int4*)&Cs[crow][cpart * 32 + 16] = v2;
        *(int4*)&Cs[crow][cpart * 32 + 24] = v3;
        __syncthreads();

        #pragma unroll
        for (int t = 0; t < 4; ++t) {       // 4 tiles of 16 centers
            int cl = t * 16 + l15;          // local center row in LDS
            int ci = chunk * 64 + cl;       // global center index
            half8 b0 = *(const half8*)&Cs[cl][lk * 8];
            half8 b1 = *(const half8*)&Cs[cl][lk * 8 + 32];
            half8 b2 = *(const half8*)&Cs[cl][lk * 8 + 64];
            half8 b3 = *(const half8*)&Cs[cl][lk * 8 + 96];
            float cc = c2[ci];
            f32x4 acc = (f32x4){0.f, 0.f, 0.f, 0.f};
            acc = __builtin_amdgcn_mfma_f32_16x16x32_f16(xa[0], b0, acc, 0, 0, 0);
            acc = __builtin_amdgcn_mfma_f32_16x16x32_f16(xa[1], b1, acc, 0, 0, 0);
            acc = __builtin_amdgcn_mfma_f32_16x16x32_f16(xa[2], b2, acc, 0, 0, 0);
            acc = __builtin_amdgcn_mfma_f32_16x16x32_f16(xa[3], b3, acc, 0, 0, 0);
            #pragma unroll
            for (int r = 0; r < 4; ++r) {
                float s = fmaf(-2.f, acc[r], cc);
                bool b = s < m1[r];         // strict: earliest center wins ties
                m2[r] = b ? m1[r] : fminf(m2[r], s);
                m1[r] = b ? s : m1[r];
                ag[r] = b ? ci : ag[r];
            }
        }
        __syncthreads();
    }

    // ---- per-sample reduce over the 16 center-columns (lanes l15=0..15) ----
    #pragma unroll
    for (int off = 1; off <= 8; off <<= 1)
        #pragma unroll
        for (int r = 0; r < 4; ++r) {
            float o1 = __shfl_xor(m1[r], off, 64);
            float o2 = __shfl_xor(m2[r], off, 64);
            int   oa = __shfl_xor(ag[r], off, 64);
            bool b = (o1 < m1[r]) || (o1 == m1[r] && oa < ag[r]);
            float lo1 = b ? o1 : m1[r];
            float hi1 = b ? m1[r] : o1;
            m2[r] = fminf(fminf(m2[r], o2), hi1);
            m1[r] = lo1;
            ag[r] = b ? oa : ag[r];
        }

    // ---- output: lane l15==0 of each row-group writes its 4 samples ----
    if (l15 == 0) {
        #pragma unroll
        for (int r = 0; r < 4; ++r) {
            int i = sbase + lk * 4 + r;
            labF[i] = (float)ag[r];
            labI[i] = ag[r];
            mindist[i] = m1[r];             // without ||x||^2 (added at loss)
            if (m2[r] - m1[r] < TAU1) {
                int p = atomicAdd(flagCount, 1);
                if (p < FLAG_CAP) flags[p] = i;
            }
        }
    }
}

// Middle stage: gather flagged samples 64/tile, re-resolve with 3-term f16
// Markidis MFMA (xh*ch + xh*cl + xl*ch). Grid-stride; nf read on device.
__global__ __launch_bounds__(256, 2) void k_mid(
    const float* __restrict__ X, const _Float16* __restrict__ Ch,
    const _Float16* __restrict__ Cl, const float* __restrict__ c2,
    const int* __restrict__ flagCount, const int* __restrict__ flags,
    float* __restrict__ labF, float* __restrict__ mindist, int* __restrict__ labI,
    int* __restrict__ flags2, int* __restrict__ flagCount2)
{
    __shared__ _Float16 Ah[64][136];
    __shared__ _Float16 Al[64][136];
    __shared__ float red1[4][64];
    __shared__ float red2[4][64];
    __shared__ int   reda[4][64];
    __shared__ int   sidx[64];

    int nf = *flagCount;
    if (nf > FLAG_CAP) nf = FLAG_CAP;
    int ntile = (nf + 63) >> 6;
    int tid = threadIdx.x;
    int wave = tid >> 6, lane = tid & 63;
    int l15 = lane & 15, lk = lane >> 4;

    for (int t = blockIdx.x; t < ntile; t += gridDim.x) {
        if (tid < 64) {
            int p = t * 64 + tid;
            sidx[tid] = flags[p < nf ? p : nf - 1];   // tail: duplicate last (idempotent)
        }
        __syncthreads();
        {
            int row = tid >> 2, part = tid & 3;
            const float4* src = (const float4*)(X + (size_t)sidx[row] * D + part * 32);
            #pragma unroll
            for (int j = 0; j < 8; ++j) {
                float4 v = src[j];
                H4 uh, ul;
                uh.h[0] = (_Float16)v.x; ul.h[0] = (_Float16)(v.x - (float)uh.h[0]);
                uh.h[1] = (_Float16)v.y; ul.h[1] = (_Float16)(v.y - (float)uh.h[1]);
                uh.h[2] = (_Float16)v.z; ul.h[2] = (_Float16)(v.z - (float)uh.h[2]);
                uh.h[3] = (_Float16)v.w; ul.h[3] = (_Float16)(v.w - (float)uh.h[3]);
                *(short4*)&Ah[row][part * 32 + j * 4] = uh.s4;
                *(short4*)&Al[row][part * 32 + j * 4] = ul.s4;
            }
        }
        __syncthreads();

        float m1[4], m2[4]; int ag[4];
        #pragma unroll
        for (int n = 0; n < 4; ++n) { m1[n] = 3.4e38f; m2[n] = 3.4e38f; ag[n] = 0; }

        for (int chunk = 0; chunk < 8; ++chunk) {
            int cb = chunk * 64 + wave * 16;
            const half8* pch = (const half8*)(Ch + (size_t)(cb + l15) * D + lk * 8);
            const half8* pcl = (const half8*)(Cl + (size_t)(cb + l15) * D + lk * 8);
            half8 ah[4], al[4];
            #pragma unroll
            for (int kk = 0; kk < 4; ++kk) { ah[kk] = pch[kk * 4]; al[kk] = pcl[kk * 4]; }
            f32x4 acc[4];
            #pragma unroll
            for (int n = 0; n < 4; ++n) acc[n] = (f32x4){0.f, 0.f, 0.f, 0.f};
            #pragma unroll
            for (int kk = 0; kk < 4; ++kk) {
                half8 xh[4], xl[4];
                #pragma unroll
                for (int n = 0; n < 4; ++n) {
                    xh[n] = *(const half8*)&Ah[n * 16 + l15][kk * 32 + lk * 8];
                    xl[n] = *(const half8*)&Al[n * 16 + l15][kk * 32 + lk * 8];
                }
                #pragma unroll
                for (int n = 0; n < 4; ++n)
                    acc[n] = __builtin_amdgcn_mfma_f32_16x16x32_f16(ah[kk], xh[n], acc[n], 0, 0, 0);
                #pragma unroll
                for (int n = 0; n < 4; ++n)
                    acc[n] = __builtin_amdgcn_mfma_f32_16x16x32_f16(al[kk], xh[n], acc[n], 0, 0, 0);
                #pragma unroll
                for (int n = 0; n < 4; ++n)
                    acc[n] = __builtin_amdgcn_mfma_f32_16x16x32_f16(ah[kk], xl[n], acc[n], 0, 0, 0);
            }
            float cc[4];
            #pragma unroll
            for (int r = 0; r < 4; ++r) cc[r] = c2[cb + lk * 4 + r];
            #pragma unroll
            for (int n = 0; n < 4; ++n)
                #pragma unroll
                for (int r = 0; r < 4; ++r) {
                    float s = fmaf(-2.f, acc[n][r], cc[r]);
                    int ci = cb + lk * 4 + r;
                    bool b = s < m1[n];
                    m2[n] = b ? m1[n] : fminf(m2[n], s);
                    m1[n] = b ? s : m1[n];
                    ag[n] = b ? ci : ag[n];
                }
        }

        #pragma unroll
        for (int off = 16; off <= 32; off <<= 1)
            #pragma unroll
            for (int n = 0; n < 4; ++n) {
                float o1 = __shfl_xor(m1[n], off, 64);
                float o2 = __shfl_xor(m2[n], off, 64);
                int   oa = __shfl_xor(ag[n], off, 64);
                bool b = (o1 < m1[n]) || (o1 == m1[n] && oa < ag[n]);
                float lo1 = b ? o1 : m1[n];
                float hi1 = b ? m1[n] : o1;
                m2[n] = fminf(fminf(m2[n], o2), hi1);
                m1[n] = lo1;
                ag[n] = b ? oa : ag[n];
            }
        if (lane < 16) {
            #pragma unroll
            for (int n = 0; n < 4; ++n) {
                red1[wave][n * 16 + l15] = m1[n];
                red2[wave][n * 16 + l15] = m2[n];
                reda[wave][n * 16 + l15] = ag[n];
            }
        }
        __syncthreads();

        if (tid < 64) {
            float M1 = red1[0][tid], M2 = red2[0][tid]; int A = reda[0][tid];
            #pragma unroll
            for (int w = 1; w < 4; ++w) {
                float o1 = red1[w][tid], o2 = red2[w][tid]; int oa = reda[w][tid];
                bool b = (o1 < M1) || (o1 == M1 && oa < A);
                float lo1 = b ? o1 : M1;
                float hi1 = b ? M1 : o1;
                M2 = fminf(fminf(M2, o2), hi1);
                M1 = lo1;
                A = b ? oa : A;
            }
            int i = sidx[tid];
            labF[i] = (float)A;
            labI[i] = A;
            mindist[i] = M1;
            bool fl = (M2 - M1 < TAU2);
            unsigned long long mask = __ballot(fl);
            int nfl = (int)__popcll(mask);
            int base = 0;
            if (tid == 0 && nfl) base = atomicAdd(flagCount2, nfl);
            base = __shfl(base, 0, 64);
            if (fl) {
                int pos = base + (int)__popcll(mask & ((1ull << tid) - 1ull));
                if (pos < FLAG2_CAP) flags2[pos] = i;
            }
        }
        __syncthreads();   // protect sidx/Ah/Al before next tile
    }
}

__global__ void k_refine(const float* __restrict__ X, const float* __restrict__ C,
                         const int* __restrict__ flagCount2, const int* __restrict__ flags2,
                         float* __restrict__ labF, float* __restrict__ mindist,
                         int* __restrict__ labI)
{
    int nf = *flagCount2;
    if (nf > FLAG2_CAP) nf = FLAG2_CAP;
    int lane = threadIdx.x;  // block of 64 = 1 wave
    for (int f = blockIdx.x; f < nf; f += gridDim.x) {
        int i = flags2[f];
        const float* xr = X + (size_t)i * D;
        double best = 1e300;
        int bestk = K;
        for (int k = lane; k < K; k += 64) {
            const float* ck = C + (size_t)k * D;
            double dot = 0.0, cc = 0.0;
            for (int d = 0; d < D; ++d) {
                double cd = (double)ck[d];
                dot = fma((double)xr[d], cd, dot);
                cc  = fma(cd, cd, cc);
            }
            double s = cc - 2.0 * dot;
            if (s < best) { best = s; bestk = k; }
        }
        #pragma unroll
        for (int off = 32; off > 0; off >>= 1) {
            double ob = __shfl_xor(best, off, 64);
            int okk   = __shfl_xor(bestk, off, 64);
            if (ob < best || (ob == best && okk < bestk)) { best = ob; bestk = okk; }
        }
        if (lane == 0) {
            labF[i] = (float)bestk;
            labI[i] = bestk;
            mindist[i] = (float)best;
        }
    }
}

// Per-block histogram via LDS atomics + fused loss partial sum.
__global__ __launch_bounds__(256) void k_bhl(const int* __restrict__ labI,
                                             const float* __restrict__ mindist,
                                             int* __restrict__ H,
                                             double* __restrict__ lossSum) {
    __shared__ int h[K];
    __shared__ double shd[4];
    for (int c = threadIdx.x; c < K; c += 256) h[c] = 0;
    __syncthreads();
    int base = blockIdx.x * ITEMS;
    double s = 0.0;
    #pragma unroll
    for (int it = 0; it < ITEMS / 256; ++it) {
        int i = base + it * 256 + threadIdx.x;
        atomicAdd(&h[labI[i]], 1);
        s += (double)mindist[i];
    }
    __syncthreads();
    for (int c = threadIdx.x; c < K; c += 256) H[blockIdx.x * K + c] = h[c];
    #pragma unroll
    for (int off = 32; off > 0; off >>= 1) s += __shfl_xor(s, off, 64);
    int wid = threadIdx.x >> 6, lane = threadIdx.x & 63;
    if (lane == 0) shd[wid] = s;
    __syncthreads();
    if (threadIdx.x == 0)
        atomicAdd(lossSum, (shd[0] + shd[1]) + (shd[2] + shd[3]));
}

// Column-scan H (per center over blocks) + block-wide prefix scan of totals.
__global__ void k_sc(int* __restrict__ H, int* __restrict__ counts) {
    __shared__ int sh[K];
    int c = threadIdx.x;
    int run = 0;
    for (int b = 0; b < NB; ++b) { int t = H[b * K + c]; H[b * K + c] = run; run += t; }
    counts[c] = run;
    sh[c] = run;
    __syncthreads();
    int my = run;
    for (int off = 1; off < K; off <<= 1) {
        int v = (c >= off) ? sh[c - off] : 0;
        __syncthreads();
        sh[c] += v;
        __syncthreads();
    }
    int excl = sh[c] - my;
    for (int b = 0; b < NB; ++b) H[b * K + c] += excl;
}

// Scatter with per-block LDS cursors — zero global atomics.
__global__ __launch_bounds__(256) void k_scatter2(const int* __restrict__ labI,
                                                  const int* __restrict__ H,
                                                  int* __restrict__ bucket) {
    __shared__ int cur[K];
    for (int c = threadIdx.x; c < K; c += 256) cur[c] = H[blockIdx.x * K + c];
    __syncthreads();
    int base = blockIdx.x * ITEMS;
    #pragma unroll
    for (int it = 0; it < ITEMS / 256; ++it) {
        int i = base + it * 256 + threadIdx.x;
        int pos = atomicAdd(&cur[labI[i]], 1);
        bucket[pos] = i;
    }
}

// Fixed segments of sorted bucket; int64 fixed-point accumulation is
// order-independent -> deterministic despite nondeterministic scatter order.
// Also accumulates sum ||x||^2 (every X row visited exactly once here).
__global__ __launch_bounds__(128) void k_sumseg(
    const float* __restrict__ X, const int* __restrict__ labI,
    const int* __restrict__ bucket, unsigned long long* __restrict__ acc,
    double* __restrict__ x2Sum)
{
    int d = threadIdx.x;
    int beg = blockIdx.x * SEG;
    long long s = 0;
    double s2 = 0.0;
    int prev = -1;
    for (int j = beg; j < beg + SEG; ++j) {
        int idx = bucket[j];
        int lab = labI[idx];                 // uniform across the block
        if (lab != prev) {
            if (prev >= 0) atomicAdd(&acc[(size_t)prev * D + d], (unsigned long long)s);
            s = 0; prev = lab;
        }
        float v = X[(size_t)idx * D + d];
        s += (long long)__float2int_rn(v * FIXSCALE);
        s2 = fma((double)v, (double)v, s2);
    }
    if (prev >= 0) atomicAdd(&acc[(size_t)prev * D + d], (unsigned long long)s);
    #pragma unroll
    for (int off = 32; off > 0; off >>= 1) s2 += __shfl_xor(s2, off, 64);
    __shared__ double shx[2];
    int wid = d >> 6;
    if ((d & 63) == 0) shx[wid] = s2;
    __syncthreads();
    if (d == 0) atomicAdd(&x2Sum[blockIdx.x & 7], shx[0] + shx[1]);
}

__global__ void k_avg(const float* __restrict__ C, const int* __restrict__ cnt,
                      const int* __restrict__ counts,
                      const unsigned long long* __restrict__ acc,
                      float* __restrict__ outC, float* __restrict__ outCnt,
                      const double* __restrict__ lossSum,
                      const double* __restrict__ x2Sum, float* __restrict__ outLoss)
{
    int t = blockIdx.x * blockDim.x + threadIdx.x;   // over K*D
    int c = t >> 7, d = t & 127;
    double s = (double)(long long)acc[t] * INVFIX;
    int m = counts[c], n0 = cnt[c];
    double nm = (double)(n0 + m);
    outC[t] = (float)(((double)n0 * (double)C[t] + s) / nm);
    if (d == 0) outCnt[c] = (float)(n0 + m);
    if (t == 0) {
        double x2 = 0.0;
        #pragma unroll
        for (int j = 0; j < 8; ++j) x2 += x2Sum[j];
        outLoss[0] = (float)((*lossSum + x2) / (double)NS);
    }
}

extern "C" void kernel_launch(void* const* d_in, const int* in_sizes, int n_in,
                              void* d_out, int out_size, void* d_ws, size_t ws_size,
                              hipStream_t stream)
{
    const float* X  = (const float*)d_in[0];
    const float* C  = (const float*)d_in[1];
    const int* cnt  = (const int*)d_in[2];

    float* out     = (float*)d_out;
    float* outLoss = out;
    float* outLab  = out + 1;
    float* outCen  = out + 1 + NS;
    float* outCnt  = out + 1 + NS + (size_t)K * D;

    char* ws = (char*)d_ws;
    double* lossSum = (double*)(ws + 0);
    double* x2Sum   = (double*)(ws + 8);
    int* flagCount  = (int*)(ws + 72);
    int* flagCount2 = (int*)(ws + 76);
    float* c2       = (float*)(ws + 80);
    int* counts     = (int*)(ws + 2128);
    float* mindist  = (float*)(ws + 4176);
    int* labI       = (int*)(ws + 528464);
    int* flags      = (int*)(ws + 1052752);
    int* flags2     = (int*)(ws + 1314896);
    int* H          = (int*)(ws + 1445968);
    int* bucket     = (int*)(ws + 1577040);
    unsigned long long* acc = (unsigned long long*)(ws + 2101328);
    _Float16* Ch    = (_Float16*)(ws + 2625616);
    _Float16* Cl    = (_Float16*)(ws + 2756688);

    hipMemsetAsync(d_ws, 0, 80, stream);                        // lossSum, x2Sum, flagCounts
    hipMemsetAsync(ws + 2101328, 0, (size_t)K * D * 8, stream); // acc
    k_prep<<<K / 4, 256, 0, stream>>>(C, c2, Ch, Cl);
    k_dist<<<NS / 64, 256, 0, stream>>>(X, Ch, c2, outLab, mindist, labI, flags, flagCount);
    k_mid<<<512, 256, 0, stream>>>(X, Ch, Cl, c2, flagCount, flags,
                                   outLab, mindist, labI, flags2, flagCount2);
    k_refine<<<2048, 64, 0, stream>>>(X, C, flagCount2, flags2, outLab, mindist, labI);
    k_bhl<<<NB, 256, 0, stream>>>(labI, mindist, H, lossSum);
    k_sc<<<1, K, 0, stream>>>(H, counts);
    k_scatter2<<<NB, 256, 0, stream>>>(labI, H, bucket);
    k_sumseg<<<NS / SEG, 128, 0, stream>>>(X, labI, bucket, acc, x2Sum);
    k_avg<<<K * D / 256, 256, 0, stream>>>(C, cnt, counts, acc, outCen, outCnt,
                                           lossSum, x2Sum, outLoss);
}

// Round 12
// 171.830 us; speedup vs baseline: 1.5237x; 1.1681x over previous
//
#include <hip/hip_runtime.h>

constexpr int NS = 131072;
constexpr int D  = 128;
constexpr int K  = 512;
constexpr int FLAG_CAP  = 65536;
constexpr int FLAG2_CAP = 32768;
constexpr float TAU1 = 0.05f;     // f16 single-pass: sigma_diff ~ 0.0065 -> ~8 sigma
constexpr float TAU2 = 2e-3f;     // f16 3-term: sigma ~ 2e-5 -> 100 sigma
constexpr int SEG = 32;
constexpr int NB = 64;            // scatter blocks
constexpr int ITEMS = NS / NB;    // 2048 items per scatter block
constexpr float FIXSCALE = 1048576.0f;       // 2^20
constexpr double INVFIX  = 1.0 / 1048576.0;

using half8 = __attribute__((ext_vector_type(8))) _Float16;
using f32x4 = __attribute__((ext_vector_type(4))) float;

// ws layout (bytes):
// 0:       double lossSum
// 8:       double x2Sum[8]    -> 72
// 72:      int flagCount; 76: int flagCount2 -> 80
// 80:      float c2[K]        -> 2128
// 2128:    int counts[K]      -> 4176
// 4176:    float mindist[NS]  -> 528464   (min1 WITHOUT ||x||^2)
// 528464:  int labI[NS]       -> 1052752
// 1052752: int flags[65536]   -> 1314896
// 1314896: int flags2[32768]  -> 1445968
// 1445968: int H[NB*K]        -> 1577040
// 1577040: int bucket[NS]     -> 2101328
// 2101328: u64 acc[K*D]       -> 2625616
// 2625616: f16 Ch[K*D]        -> 2756688
// 2756688: f16 Cl[K*D]        -> 2887760

union H4 { short4 s4; _Float16 h[4]; };
union H8 { half8 v; _Float16 h[8]; };

// Fused: c2 = ||c||^2 (f32) and C -> f16 (hi, lo) limbs. One wave per center.
__global__ void k_prep(const float* __restrict__ C, float* __restrict__ c2,
                       _Float16* __restrict__ Ch, _Float16* __restrict__ Cl) {
    int wave = (blockIdx.x * blockDim.x + threadIdx.x) >> 6;
    int lane = threadIdx.x & 63;
    const float* ck = C + (size_t)wave * D;
    float a = ck[lane], b = ck[lane + 64];
    _Float16 ha = (_Float16)a, hb = (_Float16)b;
    size_t o = (size_t)wave * D + lane;
    Ch[o] = ha;        Cl[o] = (_Float16)(a - (float)ha);
    Ch[o + 64] = hb;   Cl[o + 64] = (_Float16)(b - (float)hb);
    float s = fmaf(a, a, b * b);
    #pragma unroll
    for (int off = 32; off > 0; off >>= 1) s += __shfl_xor(s, off, 64);
    if (lane == 0) c2[wave] = s;
}

// f16 MFMA distance + per-sample argmin. Sample-stationary, 32 samples/wave
// (two A-fragment sets amortize each b-read over 8 MFMAs), LDS-staged center
// chunks shared block-wide. acc chains sequenced (set0 retires before set1)
// to cap live VGPRs. D layout: row = sample = (lane>>4)*4+reg, col = lane&15.
__global__ __launch_bounds__(256) void k_dist(
    const float* __restrict__ X, const _Float16* __restrict__ Ch,
    const float* __restrict__ c2,
    float* __restrict__ labF, float* __restrict__ mindist, int* __restrict__ labI,
    int* __restrict__ flags, int* __restrict__ flagCount)
{
    __shared__ _Float16 Cs[64][136];        // 272 B rows: 16B-aligned
    __shared__ float sC2[K];

    int tid = threadIdx.x;
    int wave = tid >> 6, lane = tid & 63;
    int l15 = lane & 15, lk = lane >> 4;
    int sbase = blockIdx.x * 128 + wave * 32;

    sC2[tid] = c2[tid];
    sC2[tid + 256] = c2[tid + 256];

    // ---- A fragments: 2 sets x 16 samples, f32 -> f16 (32 VGPR) ----
    half8 xa0[4], xa1[4];
    {
        const float* xp0 = X + (size_t)(sbase + l15) * D + lk * 8;
        const float* xp1 = X + (size_t)(sbase + 16 + l15) * D + lk * 8;
        #pragma unroll
        for (int kk = 0; kk < 4; ++kk) {
            float4 a = *(const float4*)(xp0 + kk * 32);
            float4 b = *(const float4*)(xp0 + kk * 32 + 4);
            H8 u;
            u.h[0] = (_Float16)a.x; u.h[1] = (_Float16)a.y;
            u.h[2] = (_Float16)a.z; u.h[3] = (_Float16)a.w;
            u.h[4] = (_Float16)b.x; u.h[5] = (_Float16)b.y;
            u.h[6] = (_Float16)b.z; u.h[7] = (_Float16)b.w;
            xa0[kk] = u.v;
        }
        #pragma unroll
        for (int kk = 0; kk < 4; ++kk) {
            float4 a = *(const float4*)(xp1 + kk * 32);
            float4 b = *(const float4*)(xp1 + kk * 32 + 4);
            H8 u;
            u.h[0] = (_Float16)a.x; u.h[1] = (_Float16)a.y;
            u.h[2] = (_Float16)a.z; u.h[3] = (_Float16)a.w;
            u.h[4] = (_Float16)b.x; u.h[5] = (_Float16)b.y;
            u.h[6] = (_Float16)b.z; u.h[7] = (_Float16)b.w;
            xa1[kk] = u.v;
        }
    }

    float m1a[4], m2a[4], m1b[4], m2b[4];
    int aga[4], agb[4];
    #pragma unroll
    for (int r = 0; r < 4; ++r) {
        m1a[r] = 3.4e38f; m2a[r] = 3.4e38f; aga[r] = 0;
        m1b[r] = 3.4e38f; m2b[r] = 3.4e38f; agb[r] = 0;
    }

    int crow = tid >> 2, cpart = tid & 3;   // staging role: 4 threads per center row
    for (int chunk = 0; chunk < 8; ++chunk) {
        // ---- stage 64 centers (16 KB) into LDS, cooperatively ----
        const int4* src = (const int4*)(Ch + (size_t)(chunk * 64 + crow) * D + cpart * 32);
        int4 v0 = src[0], v1 = src[1], v2 = src[2], v3 = src[3];
        *(int4*)&Cs[crow][cpart * 32]      = v0;
        *(int4*)&Cs[crow][cpart * 32 + 8]  = v1;
        *(int4*)&Cs[crow][cpart * 32 + 16] = v2;
        *(int4*)&Cs[crow][cpart * 32 + 24] = v3;
        __syncthreads();

        #pragma unroll
        for (int t = 0; t < 4; ++t) {       // 4 tiles of 16 centers
            int cl = t * 16 + l15;          // local center row in LDS
            int ci = chunk * 64 + cl;       // global center index
            half8 b0 = *(const half8*)&Cs[cl][lk * 8];
            half8 b1 = *(const half8*)&Cs[cl][lk * 8 + 32];
            half8 b2 = *(const half8*)&Cs[cl][lk * 8 + 64];
            half8 b3 = *(const half8*)&Cs[cl][lk * 8 + 96];
            float cc = sC2[ci];
            // set 0
            f32x4 acc = (f32x4){0.f, 0.f, 0.f, 0.f};
            acc = __builtin_amdgcn_mfma_f32_16x16x32_f16(xa0[0], b0, acc, 0, 0, 0);
            acc = __builtin_amdgcn_mfma_f32_16x16x32_f16(xa0[1], b1, acc, 0, 0, 0);
            acc = __builtin_amdgcn_mfma_f32_16x16x32_f16(xa0[2], b2, acc, 0, 0, 0);
            acc = __builtin_amdgcn_mfma_f32_16x16x32_f16(xa0[3], b3, acc, 0, 0, 0);
            #pragma unroll
            for (int r = 0; r < 4; ++r) {
                float s = fmaf(-2.f, acc[r], cc);
                bool b = s < m1a[r];
                m2a[r] = fminf(m2a[r], fmaxf(m1a[r], s));
                m1a[r] = b ? s : m1a[r];
                aga[r] = b ? ci : aga[r];
            }
            // set 1
            acc = (f32x4){0.f, 0.f, 0.f, 0.f};
            acc = __builtin_amdgcn_mfma_f32_16x16x32_f16(xa1[0], b0, acc, 0, 0, 0);
            acc = __builtin_amdgcn_mfma_f32_16x16x32_f16(xa1[1], b1, acc, 0, 0, 0);
            acc = __builtin_amdgcn_mfma_f32_16x16x32_f16(xa1[2], b2, acc, 0, 0, 0);
            acc = __builtin_amdgcn_mfma_f32_16x16x32_f16(xa1[3], b3, acc, 0, 0, 0);
            #pragma unroll
            for (int r = 0; r < 4; ++r) {
                float s = fmaf(-2.f, acc[r], cc);
                bool b = s < m1b[r];
                m2b[r] = fminf(m2b[r], fmaxf(m1b[r], s));
                m1b[r] = b ? s : m1b[r];
                agb[r] = b ? ci : agb[r];
            }
        }
        __syncthreads();
    }

    // ---- per-sample reduce over the 16 center-columns (lanes l15=0..15) ----
    #pragma unroll
    for (int off = 1; off <= 8; off <<= 1) {
        #pragma unroll
        for (int r = 0; r < 4; ++r) {
            float o1 = __shfl_xor(m1a[r], off, 64);
            float o2 = __shfl_xor(m2a[r], off, 64);
            int   oa = __shfl_xor(aga[r], off, 64);
            bool b = (o1 < m1a[r]) || (o1 == m1a[r] && oa < aga[r]);
            float lo1 = b ? o1 : m1a[r];
            float hi1 = b ? m1a[r] : o1;
            m2a[r] = fminf(fminf(m2a[r], o2), hi1);
            m1a[r] = lo1;
            aga[r] = b ? oa : aga[r];
        }
        #pragma unroll
        for (int r = 0; r < 4; ++r) {
            float o1 = __shfl_xor(m1b[r], off, 64);
            float o2 = __shfl_xor(m2b[r], off, 64);
            int   oa = __shfl_xor(agb[r], off, 64);
            bool b = (o1 < m1b[r]) || (o1 == m1b[r] && oa < agb[r]);
            float lo1 = b ? o1 : m1b[r];
            float hi1 = b ? m1b[r] : o1;
            m2b[r] = fminf(fminf(m2b[r], o2), hi1);
            m1b[r] = lo1;
            agb[r] = b ? oa : agb[r];
        }
    }

    // ---- output: lane l15==0 of each row-group writes its 2x4 samples ----
    if (l15 == 0) {
        #pragma unroll
        for (int r = 0; r < 4; ++r) {
            int i = sbase + lk * 4 + r;
            labF[i] = (float)aga[r];
            labI[i] = aga[r];
            mindist[i] = m1a[r];            // without ||x||^2 (added at loss)
            if (m2a[r] - m1a[r] < TAU1) {
                int p = atomicAdd(flagCount, 1);
                if (p < FLAG_CAP) flags[p] = i;
            }
        }
        #pragma unroll
        for (int r = 0; r < 4; ++r) {
            int i = sbase + 16 + lk * 4 + r;
            labF[i] = (float)agb[r];
            labI[i] = agb[r];
            mindist[i] = m1b[r];
            if (m2b[r] - m1b[r] < TAU1) {
                int p = atomicAdd(flagCount, 1);
                if (p < FLAG_CAP) flags[p] = i;
            }
        }
    }
}

// Middle stage: gather flagged samples 64/tile, re-resolve with 3-term f16
// Markidis MFMA (xh*ch + xh*cl + xl*ch). Grid-stride; nf read on device.
__global__ __launch_bounds__(256, 2) void k_mid(
    const float* __restrict__ X, const _Float16* __restrict__ Ch,
    const _Float16* __restrict__ Cl, const float* __restrict__ c2,
    const int* __restrict__ flagCount, const int* __restrict__ flags,
    float* __restrict__ labF, float* __restrict__ mindist, int* __restrict__ labI,
    int* __restrict__ flags2, int* __restrict__ flagCount2)
{
    __shared__ _Float16 Ah[64][136];
    __shared__ _Float16 Al[64][136];
    __shared__ float red1[4][64];
    __shared__ float red2[4][64];
    __shared__ int   reda[4][64];
    __shared__ int   sidx[64];

    int nf = *flagCount;
    if (nf > FLAG_CAP) nf = FLAG_CAP;
    int ntile = (nf + 63) >> 6;
    int tid = threadIdx.x;
    int wave = tid >> 6, lane = tid & 63;
    int l15 = lane & 15, lk = lane >> 4;

    for (int t = blockIdx.x; t < ntile; t += gridDim.x) {
        if (tid < 64) {
            int p = t * 64 + tid;
            sidx[tid] = flags[p < nf ? p : nf - 1];   // tail: duplicate last (idempotent)
        }
        __syncthreads();
        {
            int row = tid >> 2, part = tid & 3;
            const float4* src = (const float4*)(X + (size_t)sidx[row] * D + part * 32);
            #pragma unroll
            for (int j = 0; j < 8; ++j) {
                float4 v = src[j];
                H4 uh, ul;
                uh.h[0] = (_Float16)v.x; ul.h[0] = (_Float16)(v.x - (float)uh.h[0]);
                uh.h[1] = (_Float16)v.y; ul.h[1] = (_Float16)(v.y - (float)uh.h[1]);
                uh.h[2] = (_Float16)v.z; ul.h[2] = (_Float16)(v.z - (float)uh.h[2]);
                uh.h[3] = (_Float16)v.w; ul.h[3] = (_Float16)(v.w - (float)uh.h[3]);
                *(short4*)&Ah[row][part * 32 + j * 4] = uh.s4;
                *(short4*)&Al[row][part * 32 + j * 4] = ul.s4;
            }
        }
        __syncthreads();

        float m1[4], m2[4]; int ag[4];
        #pragma unroll
        for (int n = 0; n < 4; ++n) { m1[n] = 3.4e38f; m2[n] = 3.4e38f; ag[n] = 0; }

        for (int chunk = 0; chunk < 8; ++chunk) {
            int cb = chunk * 64 + wave * 16;
            const half8* pch = (const half8*)(Ch + (size_t)(cb + l15) * D + lk * 8);
            const half8* pcl = (const half8*)(Cl + (size_t)(cb + l15) * D + lk * 8);
            half8 ah[4], al[4];
            #pragma unroll
            for (int kk = 0; kk < 4; ++kk) { ah[kk] = pch[kk * 4]; al[kk] = pcl[kk * 4]; }
            f32x4 acc[4];
            #pragma unroll
            for (int n = 0; n < 4; ++n) acc[n] = (f32x4){0.f, 0.f, 0.f, 0.f};
            #pragma unroll
            for (int kk = 0; kk < 4; ++kk) {
                half8 xh[4], xl[4];
                #pragma unroll
                for (int n = 0; n < 4; ++n) {
                    xh[n] = *(const half8*)&Ah[n * 16 + l15][kk * 32 + lk * 8];
                    xl[n] = *(const half8*)&Al[n * 16 + l15][kk * 32 + lk * 8];
                }
                #pragma unroll
                for (int n = 0; n < 4; ++n)
                    acc[n] = __builtin_amdgcn_mfma_f32_16x16x32_f16(ah[kk], xh[n], acc[n], 0, 0, 0);
                #pragma unroll
                for (int n = 0; n < 4; ++n)
                    acc[n] = __builtin_amdgcn_mfma_f32_16x16x32_f16(al[kk], xh[n], acc[n], 0, 0, 0);
                #pragma unroll
                for (int n = 0; n < 4; ++n)
                    acc[n] = __builtin_amdgcn_mfma_f32_16x16x32_f16(ah[kk], xl[n], acc[n], 0, 0, 0);
            }
            float cc[4];
            #pragma unroll
            for (int r = 0; r < 4; ++r) cc[r] = c2[cb + lk * 4 + r];
            #pragma unroll
            for (int n = 0; n < 4; ++n)
                #pragma unroll
                for (int r = 0; r < 4; ++r) {
                    float s = fmaf(-2.f, acc[n][r], cc[r]);
                    int ci = cb + lk * 4 + r;
                    bool b = s < m1[n];
                    m2[n] = b ? m1[n] : fminf(m2[n], s);
                    m1[n] = b ? s : m1[n];
                    ag[n] = b ? ci : ag[n];
                }
        }

        #pragma unroll
        for (int off = 16; off <= 32; off <<= 1)
            #pragma unroll
            for (int n = 0; n < 4; ++n) {
                float o1 = __shfl_xor(m1[n], off, 64);
                float o2 = __shfl_xor(m2[n], off, 64);
                int   oa = __shfl_xor(ag[n], off, 64);
                bool b = (o1 < m1[n]) || (o1 == m1[n] && oa < ag[n]);
                float lo1 = b ? o1 : m1[n];
                float hi1 = b ? m1[n] : o1;
                m2[n] = fminf(fminf(m2[n], o2), hi1);
                m1[n] = lo1;
                ag[n] = b ? oa : ag[n];
            }
        if (lane < 16) {
            #pragma unroll
            for (int n = 0; n < 4; ++n) {
                red1[wave][n * 16 + l15] = m1[n];
                red2[wave][n * 16 + l15] = m2[n];
                reda[wave][n * 16 + l15] = ag[n];
            }
        }
        __syncthreads();

        if (tid < 64) {
            float M1 = red1[0][tid], M2 = red2[0][tid]; int A = reda[0][tid];
            #pragma unroll
            for (int w = 1; w < 4; ++w) {
                float o1 = red1[w][tid], o2 = red2[w][tid]; int oa = reda[w][tid];
                bool b = (o1 < M1) || (o1 == M1 && oa < A);
                float lo1 = b ? o1 : M1;
                float hi1 = b ? M1 : o1;
                M2 = fminf(fminf(M2, o2), hi1);
                M1 = lo1;
                A = b ? oa : A;
            }
            int i = sidx[tid];
            labF[i] = (float)A;
            labI[i] = A;
            mindist[i] = M1;
            bool fl = (M2 - M1 < TAU2);
            unsigned long long mask = __ballot(fl);
            int nfl = (int)__popcll(mask);
            int base = 0;
            if (tid == 0 && nfl) base = atomicAdd(flagCount2, nfl);
            base = __shfl(base, 0, 64);
            if (fl) {
                int pos = base + (int)__popcll(mask & ((1ull << tid) - 1ull));
                if (pos < FLAG2_CAP) flags2[pos] = i;
            }
        }
        __syncthreads();   // protect sidx/Ah/Al before next tile
    }
}

__global__ void k_refine(const float* __restrict__ X, const float* __restrict__ C,
                         const int* __restrict__ flagCount2, const int* __restrict__ flags2,
                         float* __restrict__ labF, float* __restrict__ mindist,
                         int* __restrict__ labI)
{
    int nf = *flagCount2;
    if (nf > FLAG2_CAP) nf = FLAG2_CAP;
    int lane = threadIdx.x;  // block of 64 = 1 wave
    for (int f = blockIdx.x; f < nf; f += gridDim.x) {
        int i = flags2[f];
        const float* xr = X + (size_t)i * D;
        double best = 1e300;
        int bestk = K;
        for (int k = lane; k < K; k += 64) {
            const float* ck = C + (size_t)k * D;
            double dot = 0.0, cc = 0.0;
            for (int d = 0; d < D; ++d) {
                double cd = (double)ck[d];
                dot = fma((double)xr[d], cd, dot);
                cc  = fma(cd, cd, cc);
            }
            double s = cc - 2.0 * dot;
            if (s < best) { best = s; bestk = k; }
        }
        #pragma unroll
        for (int off = 32; off > 0; off >>= 1) {
            double ob = __shfl_xor(best, off, 64);
            int okk   = __shfl_xor(bestk, off, 64);
            if (ob < best || (ob == best && okk < bestk)) { best = ob; bestk = okk; }
        }
        if (lane == 0) {
            labF[i] = (float)bestk;
            labI[i] = bestk;
            mindist[i] = (float)best;
        }
    }
}

// Per-block histogram via LDS atomics + fused loss partial sum.
__global__ __launch_bounds__(256) void k_bhl(const int* __restrict__ labI,
                                             const float* __restrict__ mindist,
                                             int* __restrict__ H,
                                             double* __restrict__ lossSum) {
    __shared__ int h[K];
    __shared__ double shd[4];
    for (int c = threadIdx.x; c < K; c += 256) h[c] = 0;
    __syncthreads();
    int base = blockIdx.x * ITEMS;
    double s = 0.0;
    #pragma unroll
    for (int it = 0; it < ITEMS / 256; ++it) {
        int i = base + it * 256 + threadIdx.x;
        atomicAdd(&h[labI[i]], 1);
        s += (double)mindist[i];
    }
    __syncthreads();
    for (int c = threadIdx.x; c < K; c += 256) H[blockIdx.x * K + c] = h[c];
    #pragma unroll
    for (int off = 32; off > 0; off >>= 1) s += __shfl_xor(s, off, 64);
    int wid = threadIdx.x >> 6, lane = threadIdx.x & 63;
    if (lane == 0) shd[wid] = s;
    __syncthreads();
    if (threadIdx.x == 0)
        atomicAdd(lossSum, (shd[0] + shd[1]) + (shd[2] + shd[3]));
}

// Column-scan H (per center over blocks) + block-wide prefix scan of totals.
__global__ void k_sc(int* __restrict__ H, int* __restrict__ counts) {
    __shared__ int sh[K];
    int c = threadIdx.x;
    int run = 0;
    for (int b = 0; b < NB; ++b) { int t = H[b * K + c]; H[b * K + c] = run; run += t; }
    counts[c] = run;
    sh[c] = run;
    __syncthreads();
    int my = run;
    for (int off = 1; off < K; off <<= 1) {
        int v = (c >= off) ? sh[c - off] : 0;
        __syncthreads();
        sh[c] += v;
        __syncthreads();
    }
    int excl = sh[c] - my;
    for (int b = 0; b < NB; ++b) H[b * K + c] += excl;
}

// Scatter with per-block LDS cursors — zero global atomics.
__global__ __launch_bounds__(256) void k_scatter2(const int* __restrict__ labI,
                                                  const int* __restrict__ H,
                                                  int* __restrict__ bucket) {
    __shared__ int cur[K];
    for (int c = threadIdx.x; c < K; c += 256) cur[c] = H[blockIdx.x * K + c];
    __syncthreads();
    int base = blockIdx.x * ITEMS;
    #pragma unroll
    for (int it = 0; it < ITEMS / 256; ++it) {
        int i = base + it * 256 + threadIdx.x;
        int pos = atomicAdd(&cur[labI[i]], 1);
        bucket[pos] = i;
    }
}

// Fixed segments of sorted bucket; int64 fixed-point accumulation is
// order-independent -> deterministic despite nondeterministic scatter order.
// Also accumulates sum ||x||^2 (every X row visited exactly once here).
__global__ __launch_bounds__(128) void k_sumseg(
    const float* __restrict__ X, const int* __restrict__ labI,
    const int* __restrict__ bucket, unsigned long long* __restrict__ acc,
    double* __restrict__ x2Sum)
{
    int d = threadIdx.x;
    int beg = blockIdx.x * SEG;
    long long s = 0;
    double s2 = 0.0;
    int prev = -1;
    for (int j = beg; j < beg + SEG; ++j) {
        int idx = bucket[j];
        int lab = labI[idx];                 // uniform across the block
        if (lab != prev) {
            if (prev >= 0) atomicAdd(&acc[(size_t)prev * D + d], (unsigned long long)s);
            s = 0; prev = lab;
        }
        float v = X[(size_t)idx * D + d];
        s += (long long)__float2int_rn(v * FIXSCALE);
        s2 = fma((double)v, (double)v, s2);
    }
    if (prev >= 0) atomicAdd(&acc[(size_t)prev * D + d], (unsigned long long)s);
    #pragma unroll
    for (int off = 32; off > 0; off >>= 1) s2 += __shfl_xor(s2, off, 64);
    __shared__ double shx[2];
    int wid = d >> 6;
    if ((d & 63) == 0) shx[wid] = s2;
    __syncthreads();
    if (d == 0) atomicAdd(&x2Sum[blockIdx.x & 7], shx[0] + shx[1]);
}

__global__ void k_avg(const float* __restrict__ C, const int* __restrict__ cnt,
                      const int* __restrict__ counts,
                      const unsigned long long* __restrict__ acc,
                      float* __restrict__ outC, float* __restrict__ outCnt,
                      const double* __restrict__ lossSum,
                      const double* __restrict__ x2Sum, float* __restrict__ outLoss)
{
    int t = blockIdx.x * blockDim.x + threadIdx.x;   // over K*D
    int c = t >> 7, d = t & 127;
    double s = (double)(long long)acc[t] * INVFIX;
    int m = counts[c], n0 = cnt[c];
    double nm = (double)(n0 + m);
    outC[t] = (float)(((double)n0 * (double)C[t] + s) / nm);
    if (d == 0) outCnt[c] = (float)(n0 + m);
    if (t == 0) {
        double x2 = 0.0;
        #pragma unroll
        for (int j = 0; j < 8; ++j) x2 += x2Sum[j];
        outLoss[0] = (float)((*lossSum + x2) / (double)NS);
    }
}

extern "C" void kernel_launch(void* const* d_in, const int* in_sizes, int n_in,
                              void* d_out, int out_size, void* d_ws, size_t ws_size,
                              hipStream_t stream)
{
    const float* X  = (const float*)d_in[0];
    const float* C  = (const float*)d_in[1];
    const int* cnt  = (const int*)d_in[2];

    float* out     = (float*)d_out;
    float* outLoss = out;
    float* outLab  = out + 1;
    float* outCen  = out + 1 + NS;
    float* outCnt  = out + 1 + NS + (size_t)K * D;

    char* ws = (char*)d_ws;
    double* lossSum = (double*)(ws + 0);
    double* x2Sum   = (double*)(ws + 8);
    int* flagCount  = (int*)(ws + 72);
    int* flagCount2 = (int*)(ws + 76);
    float* c2       = (float*)(ws + 80);
    int* counts     = (int*)(ws + 2128);
    float* mindist  = (float*)(ws + 4176);
    int* labI       = (int*)(ws + 528464);
    int* flags      = (int*)(ws + 1052752);
    int* flags2     = (int*)(ws + 1314896);
    int* H          = (int*)(ws + 1445968);
    int* bucket     = (int*)(ws + 1577040);
    unsigned long long* acc = (unsigned long long*)(ws + 2101328);
    _Float16* Ch    = (_Float16*)(ws + 2625616);
    _Float16* Cl    = (_Float16*)(ws + 2756688);

    hipMemsetAsync(d_ws, 0, 80, stream);                        // lossSum, x2Sum, flagCounts
    hipMemsetAsync(ws + 2101328, 0, (size_t)K * D * 8, stream); // acc
    k_prep<<<K / 4, 256, 0, stream>>>(C, c2, Ch, Cl);
    k_dist<<<NS / 128, 256, 0, stream>>>(X, Ch, c2, outLab, mindist, labI, flags, flagCount);
    k_mid<<<512, 256, 0, stream>>>(X, Ch, Cl, c2, flagCount, flags,
                                   outLab, mindist, labI, flags2, flagCount2);
    k_refine<<<2048, 64, 0, stream>>>(X, C, flagCount2, flags2, outLab, mindist, labI);
    k_bhl<<<NB, 256, 0, stream>>>(labI, mindist, H, lossSum);
    k_sc<<<1, K, 0, stream>>>(H, counts);
    k_scatter2<<<NB, 256, 0, stream>>>(labI, H, bucket);
    k_sumseg<<<NS / SEG, 128, 0, stream>>>(X, labI, bucket, acc, x2Sum);
    k_avg<<<K * D / 256, 256, 0, stream>>>(C, cnt, counts, acc, outCen, outCnt,
                                           lossSum, x2Sum, outLoss);
}